// Round 3
// baseline (392.766 us; speedup 1.0000x reference)
//
#include <hip/hip_runtime.h>
#include <hip/hip_bf16.h>
#include <math.h>

#define D        64      // feature dim
#define NQ       128     // 32*4 queries
#define TS       64      // action rows per tile
#define MARGIN   0.025f  // > 2*(bf16 RNE dot error bound ~0.008) in cosine units
#define CAP      128     // max flagged tiles per query

typedef __attribute__((ext_vector_type(8))) short  short8;
typedef __attribute__((ext_vector_type(4))) float  f32x4;

__device__ inline unsigned ordf(float f) {
    unsigned u = __float_as_uint(f);
    return (u & 0x80000000u) ? ~u : (u | 0x80000000u);
}

__device__ inline short bf16bits(float f) {
    __hip_bfloat16 h = __float2bfloat16(f);
    return *(short*)&h;
}

__device__ inline float sq16(f32x4 a, f32x4 b, f32x4 c, f32x4 d) {
    float s = 0.f;
    s = fmaf(a.x, a.x, s); s = fmaf(a.y, a.y, s); s = fmaf(a.z, a.z, s); s = fmaf(a.w, a.w, s);
    s = fmaf(b.x, b.x, s); s = fmaf(b.y, b.y, s); s = fmaf(b.z, b.z, s); s = fmaf(b.w, b.w, s);
    s = fmaf(c.x, c.x, s); s = fmaf(c.y, c.y, s); s = fmaf(c.z, c.z, s); s = fmaf(c.w, c.w, s);
    s = fmaf(d.x, d.x, s); s = fmaf(d.y, d.y, s); s = fmaf(d.z, d.z, s); s = fmaf(d.w, d.w, s);
    return s;
}

__device__ inline short8 cvt8(f32x4 a, f32x4 b, float s) {
    short8 r;
    r[0] = bf16bits(a.x * s); r[1] = bf16bits(a.y * s);
    r[2] = bf16bits(a.z * s); r[3] = bf16bits(a.w * s);
    r[4] = bf16bits(b.x * s); r[5] = bf16bits(b.y * s);
    r[6] = bf16bits(b.z * s); r[7] = bf16bits(b.w * s);
    return r;
}

// K1: wave-per-tile, no LDS, no barriers. Rows AND queries normalized in fp32
// then bf16; MFMA output = cosine sims directly. Per-(q,tile) max -> tmax[q][tile].
__global__ __launch_bounds__(256, 2)
void k1_score(const float* __restrict__ pred,
              const float* __restrict__ acts,
              float* __restrict__ tmax,
              int ntiles)
{
    const int tid  = threadIdx.x;
    const int lane = tid & 63;
    const int quad = lane >> 4;     // 0..3
    const int l15  = lane & 15;
    const int wid  = blockIdx.x * 4 + (tid >> 6);
    const int nw   = gridDim.x * 4;

    // ---- B frags: all 128 queries, normalized, bf16. q = nt*16+l15, k = ks*32+quad*8+j
    short8 bf[8][2];
#pragma unroll
    for (int nt = 0; nt < 8; ++nt) {
        const int q = nt * 16 + l15;
        const float* P = pred + q * D + quad * 8;
        f32x4 v0 = *(const f32x4*)(P);
        f32x4 v1 = *(const f32x4*)(P + 4);
        f32x4 v2 = *(const f32x4*)(P + 32);
        f32x4 v3 = *(const f32x4*)(P + 36);
        float nb2 = sq16(v0, v1, v2, v3);
        nb2 += __shfl_xor(nb2, 16);       // quads hold disjoint k-slices of same q
        nb2 += __shfl_xor(nb2, 32);
        const float rnb = 1.0f / sqrtf(nb2);
        bf[nt][0] = cvt8(v0, v1, rnb);
        bf[nt][1] = cvt8(v2, v3, rnb);
    }

    for (int tile = wid; tile < ntiles; tile += nw) {
        const float* base = acts + (size_t)tile * (TS * D);

        // ---- load lane's A slices: rows mt*16+l15, cols ks*32+quad*8+[0,8)
        f32x4 af[4][2][2];
#pragma unroll
        for (int mt = 0; mt < 4; ++mt) {
            const float* rp = base + (mt * 16 + l15) * D + quad * 8;
#pragma unroll
            for (int ks = 0; ks < 2; ++ks) {
                af[mt][ks][0] = *(const f32x4*)(rp + ks * 32);
                af[mt][ks][1] = *(const f32x4*)(rp + ks * 32 + 4);
            }
        }

        // ---- in-lane norms (+2 quad shuffles), normalize, cvt to bf16 frags
        short8 abf[4][2];
#pragma unroll
        for (int mt = 0; mt < 4; ++mt) {
            float s = sq16(af[mt][0][0], af[mt][0][1], af[mt][1][0], af[mt][1][1]);
            s += __shfl_xor(s, 16);
            s += __shfl_xor(s, 32);
            const float r = 1.0f / sqrtf(s);
            abf[mt][0] = cvt8(af[mt][0][0], af[mt][0][1], r);
            abf[mt][1] = cvt8(af[mt][1][0], af[mt][1][1], r);
        }

        // ---- 8 nt-chunks of 16 queries; acc reused per chunk
#pragma unroll
        for (int nt = 0; nt < 8; ++nt) {
            f32x4 acc[4];
#pragma unroll
            for (int mt = 0; mt < 4; ++mt) acc[mt] = (f32x4){0.f, 0.f, 0.f, 0.f};
#pragma unroll
            for (int ks = 0; ks < 2; ++ks)
#pragma unroll
                for (int mt = 0; mt < 4; ++mt)
                    acc[mt] = __builtin_amdgcn_mfma_f32_16x16x32_bf16(
                        abf[mt][ks], bf[nt][ks], acc[mt], 0, 0, 0);

            float m = -3.0e38f;
#pragma unroll
            for (int mt = 0; mt < 4; ++mt) {
                m = fmaxf(m, fmaxf(fmaxf(acc[mt].x, acc[mt].y),
                                   fmaxf(acc[mt].z, acc[mt].w)));
            }
            m = fmaxf(m, __shfl_xor(m, 16));   // quads hold disjoint row sets
            m = fmaxf(m, __shfl_xor(m, 32));
            if (quad == 0)
                tmax[(size_t)(nt * 16 + l15) * ntiles + tile] = m;
        }
    }
}

// K2: one block per query. Coalesced row scan for approx max, flag tiles within
// MARGIN (provably contains the exact argmax), exact fp32 rescore.
__global__ __launch_bounds__(256, 2)
void k2_rescore(const float* __restrict__ pred,
                const float* __restrict__ acts,
                const float* __restrict__ tmax,
                float* __restrict__ out,
                int ntiles)
{
    __shared__ float wmax[4];
    __shared__ int   cnt;
    __shared__ int   list[CAP];

    const int q   = blockIdx.x;
    const int tid = threadIdx.x;
    const float* row = tmax + (size_t)q * ntiles;

    if (tid == 0) cnt = 0;
    float m = -3.0e38f;
    for (int t = tid; t < ntiles; t += 256) m = fmaxf(m, row[t]);
#pragma unroll
    for (int off = 1; off < 64; off <<= 1) m = fmaxf(m, __shfl_xor(m, off));
    if ((tid & 63) == 0) wmax[tid >> 6] = m;
    __syncthreads();
    m = fmaxf(fmaxf(wmax[0], wmax[1]), fmaxf(wmax[2], wmax[3]));
    const float thr = m - MARGIN;

    for (int t = tid; t < ntiles; t += 256) {
        if (row[t] >= thr) {
            int i = atomicAdd(&cnt, 1);
            if (i < CAP) list[i] = t;
        }
    }
    __syncthreads();
    const int n = min(cnt, CAP);

    if (tid < 64) {   // wave 0: 64 lanes = 64 rows per flagged tile
        const f32x4* P = (const f32x4*)(pred + q * D);
        unsigned long long best = 0ull;
        for (int i = 0; i < n; ++i) {
            const int r = list[i] * TS + tid;
            const f32x4* A = (const f32x4*)(acts + (size_t)r * D);
            float dot = 0.f, na2 = 0.f;
#pragma unroll
            for (int c = 0; c < 16; ++c) {
                f32x4 a = A[c];
                f32x4 p = P[c];
                dot = fmaf(a.x, p.x, dot); na2 = fmaf(a.x, a.x, na2);
                dot = fmaf(a.y, p.y, dot); na2 = fmaf(a.y, a.y, na2);
                dot = fmaf(a.z, p.z, dot); na2 = fmaf(a.z, a.z, na2);
                dot = fmaf(a.w, p.w, dot); na2 = fmaf(a.w, a.w, na2);
            }
            float sim = dot * (1.0f / sqrtf(na2));
            unsigned long long key =
                ((unsigned long long)ordf(sim) << 32) | (unsigned)(~r);
#pragma unroll
            for (int off = 1; off < 64; off <<= 1) {
                unsigned long long o = __shfl_xor(key, off);
                if (o > key) key = o;
            }
            if (key > best) best = key;
        }
        const unsigned idx = ~(unsigned)(best & 0xffffffffull);
        out[q * D + tid] = acts[(size_t)idx * D + tid];
    }
}

extern "C" void kernel_launch(void* const* d_in, const int* in_sizes, int n_in,
                              void* d_out, int out_size, void* d_ws, size_t ws_size,
                              hipStream_t stream)
{
    const float* pred = (const float*)d_in[0];   // (32,4,64)
    const float* acts = (const float*)d_in[1];   // (1000000,64)
    long n0 = in_sizes[0], n1 = in_sizes[1];
    if (n0 > n1) {                                // defensive: acts is the big one
        const float* t = pred; pred = acts; acts = t;
        long tt = n0; n0 = n1; n1 = tt;
    }
    const int N      = (int)(n1 / D);
    const int ntiles = N / TS;                    // 1e6/64 = 15625

    float* tmax = (float*)d_ws;                   // [q][tile]: 128*15625*4 = 8 MB
    float* out  = (float*)d_out;

    k1_score<<<dim3(512), dim3(256), 0, stream>>>(pred, acts, tmax, ntiles);
    k2_rescore<<<dim3(NQ), dim3(256), 0, stream>>>(pred, acts, tmax, out, ntiles);
}

// Round 4
// 383.688 us; speedup vs baseline: 1.0237x; 1.0237x over previous
//
#include <hip/hip_runtime.h>
#include <hip/hip_bf16.h>
#include <math.h>

#define D        64      // feature dim
#define NQ       128     // 32*4 queries
#define TS       64      // action rows per tile
#define ASTRIDE  72      // bf16 elems per LDS row: 144 B, 16B-aligned, <=2-way bank alias (free)
#define MARGIN   0.025f  // > 2*(bf16 RNE cosine error bound ~0.008)
#define CAP      128     // max flagged tiles per query

typedef __attribute__((ext_vector_type(8))) short  short8;
typedef __attribute__((ext_vector_type(4))) short  short4v;
typedef __attribute__((ext_vector_type(4))) float  f32x4;

__device__ inline unsigned ordf(float f) {
    unsigned u = __float_as_uint(f);
    return (u & 0x80000000u) ? ~u : (u | 0x80000000u);
}

__device__ inline short bf16bits(float f) {
    __hip_bfloat16 h = __float2bfloat16(f);
    return *(short*)&h;
}

__device__ inline float sq4(f32x4 a) {
    float s = 0.f;
    s = fmaf(a.x, a.x, s); s = fmaf(a.y, a.y, s);
    s = fmaf(a.z, a.z, s); s = fmaf(a.w, a.w, s);
    return s;
}

__device__ inline float sq16(f32x4 a, f32x4 b, f32x4 c, f32x4 d) {
    return sq4(a) + sq4(b) + sq4(c) + sq4(d);
}

__device__ inline short8 cvt8(f32x4 a, f32x4 b, float s) {
    short8 r;
    r[0] = bf16bits(a.x * s); r[1] = bf16bits(a.y * s);
    r[2] = bf16bits(a.z * s); r[3] = bf16bits(a.w * s);
    r[4] = bf16bits(b.x * s); r[5] = bf16bits(b.y * s);
    r[6] = bf16bits(b.z * s); r[7] = bf16bits(b.w * s);
    return r;
}

__device__ inline short4v cvt4(f32x4 a, float s) {
    short4v r;
    r[0] = bf16bits(a.x * s); r[1] = bf16bits(a.y * s);
    r[2] = bf16bits(a.z * s); r[3] = bf16bits(a.w * s);
    return r;
}

// K1: block-per-tile, double-buffered bf16 LDS tile. Dense block-wide staging
// loads (zero TA amplification); rows normalized in fp32 then bf16; wave w
// handles queries [32w,32w+32). One __syncthreads per tile.
__global__ __launch_bounds__(256, 3)
void k1_score(const float* __restrict__ pred,
              const float* __restrict__ acts,
              float* __restrict__ tmax,
              int ntiles)
{
    __shared__ unsigned short As[2][TS * ASTRIDE];   // normalized bf16 tiles

    const int tid  = threadIdx.x;
    const int lane = tid & 63;
    const int wv   = tid >> 6;      // 0..3
    const int quad = lane >> 4;     // 0..3
    const int l15  = lane & 15;

    // ---- B frags: wave's 32 queries, normalized, bf16. q=(wv*2+nt)*16+l15 ----
    short8 bf[2][2];
#pragma unroll
    for (int nt = 0; nt < 2; ++nt) {
        const int q = (wv * 2 + nt) * 16 + l15;
        const float* P = pred + q * D + quad * 8;
        f32x4 v0 = *(const f32x4*)(P);
        f32x4 v1 = *(const f32x4*)(P + 4);
        f32x4 v2 = *(const f32x4*)(P + 32);
        f32x4 v3 = *(const f32x4*)(P + 36);
        float nb2 = sq16(v0, v1, v2, v3);
        nb2 += __shfl_xor(nb2, 16);       // quads hold disjoint k-slices of same q
        nb2 += __shfl_xor(nb2, 32);
        const float rnb = 1.0f / sqrtf(nb2);
        bf[nt][0] = cvt8(v0, v1, rnb);
        bf[nt][1] = cvt8(v2, v3, rnb);
    }

    int tile = blockIdx.x;
    if (tile >= ntiles) return;

    // ---- prologue: stage tile into buffer 0 ----
    {
        const f32x4* src = (const f32x4*)(acts + (size_t)tile * (TS * D));
        f32x4 v[4];
#pragma unroll
        for (int i = 0; i < 4; ++i) v[i] = src[tid + i * 256];   // dense 4 KB/inst
#pragma unroll
        for (int i = 0; i < 4; ++i) {
            const int c   = tid + i * 256;
            const int row = c >> 4, col = c & 15;
            float s = sq4(v[i]);
            s += __shfl_xor(s, 1); s += __shfl_xor(s, 2);
            s += __shfl_xor(s, 4); s += __shfl_xor(s, 8);
            *(short4v*)&As[0][row * ASTRIDE + col * 4] = cvt4(v[i], 1.0f / sqrtf(s));
        }
    }
    __syncthreads();

    int p = 0;
    while (true) {
        const int tn = tile + gridDim.x;
        const bool have_next = tn < ntiles;

        // ---- issue next tile's dense loads early (overlap MFMA) ----
        f32x4 v[4];
        if (have_next) {
            const f32x4* src = (const f32x4*)(acts + (size_t)tn * (TS * D));
#pragma unroll
            for (int i = 0; i < 4; ++i) v[i] = src[tid + i * 256];
        }

        // ---- MFMA on buffer p: A-frags shared across the wave's 2 nt-chunks ----
        short8 af[4][2];
#pragma unroll
        for (int mt = 0; mt < 4; ++mt)
#pragma unroll
            for (int ks = 0; ks < 2; ++ks)
                af[mt][ks] = *(const short8*)
                    &As[p][(mt * 16 + l15) * ASTRIDE + ks * 32 + quad * 8];

        f32x4 acc[2][4];
#pragma unroll
        for (int nt = 0; nt < 2; ++nt)
#pragma unroll
            for (int mt = 0; mt < 4; ++mt) acc[nt][mt] = (f32x4){0.f, 0.f, 0.f, 0.f};
#pragma unroll
        for (int ks = 0; ks < 2; ++ks)
#pragma unroll
            for (int nt = 0; nt < 2; ++nt)
#pragma unroll
                for (int mt = 0; mt < 4; ++mt)
                    acc[nt][mt] = __builtin_amdgcn_mfma_f32_16x16x32_bf16(
                        af[mt][ks], bf[nt][ks], acc[nt][mt], 0, 0, 0);

        // ---- epilogue: per-(q,tile) max ----
#pragma unroll
        for (int nt = 0; nt < 2; ++nt) {
            float m = -3.0e38f;
#pragma unroll
            for (int mt = 0; mt < 4; ++mt)
                m = fmaxf(m, fmaxf(fmaxf(acc[nt][mt].x, acc[nt][mt].y),
                                   fmaxf(acc[nt][mt].z, acc[nt][mt].w)));
            m = fmaxf(m, __shfl_xor(m, 16));
            m = fmaxf(m, __shfl_xor(m, 32));
            if (quad == 0) {
                const int q = (wv * 2 + nt) * 16 + l15;
                tmax[(size_t)q * ntiles + tile] = m;
            }
        }

        if (!have_next) break;

        // ---- normalize+cvt next tile into buffer p^1 ----
#pragma unroll
        for (int i = 0; i < 4; ++i) {
            const int c   = tid + i * 256;
            const int row = c >> 4, col = c & 15;
            float s = sq4(v[i]);
            s += __shfl_xor(s, 1); s += __shfl_xor(s, 2);
            s += __shfl_xor(s, 4); s += __shfl_xor(s, 8);
            *(short4v*)&As[p ^ 1][row * ASTRIDE + col * 4] = cvt4(v[i], 1.0f / sqrtf(s));
        }
        __syncthreads();
        p ^= 1;
        tile = tn;
    }
}

// K2: one block per query. Coalesced scan of tmax row for approx max, flag
// tiles within MARGIN (provably contains exact argmax), exact fp32 rescore.
__global__ __launch_bounds__(256, 2)
void k2_rescore(const float* __restrict__ pred,
                const float* __restrict__ acts,
                const float* __restrict__ tmax,
                float* __restrict__ out,
                int ntiles)
{
    __shared__ float wmax[4];
    __shared__ int   cnt;
    __shared__ int   list[CAP];

    const int q   = blockIdx.x;
    const int tid = threadIdx.x;
    const float* row = tmax + (size_t)q * ntiles;

    if (tid == 0) cnt = 0;
    float m = -3.0e38f;
    for (int t = tid; t < ntiles; t += 256) m = fmaxf(m, row[t]);
#pragma unroll
    for (int off = 1; off < 64; off <<= 1) m = fmaxf(m, __shfl_xor(m, off));
    if ((tid & 63) == 0) wmax[tid >> 6] = m;
    __syncthreads();
    m = fmaxf(fmaxf(wmax[0], wmax[1]), fmaxf(wmax[2], wmax[3]));
    const float thr = m - MARGIN;

    for (int t = tid; t < ntiles; t += 256) {
        if (row[t] >= thr) {
            int i = atomicAdd(&cnt, 1);
            if (i < CAP) list[i] = t;
        }
    }
    __syncthreads();
    const int n = min(cnt, CAP);

    if (tid < 64) {   // wave 0: 64 lanes = 64 rows per flagged tile
        const f32x4* P = (const f32x4*)(pred + q * D);
        unsigned long long best = 0ull;
        for (int i = 0; i < n; ++i) {
            const int r = list[i] * TS + tid;
            const f32x4* A = (const f32x4*)(acts + (size_t)r * D);
            float dot = 0.f, na2 = 0.f;
#pragma unroll
            for (int c = 0; c < 16; ++c) {
                f32x4 a = A[c];
                f32x4 pq = P[c];
                dot = fmaf(a.x, pq.x, dot); na2 = fmaf(a.x, a.x, na2);
                dot = fmaf(a.y, pq.y, dot); na2 = fmaf(a.y, a.y, na2);
                dot = fmaf(a.z, pq.z, dot); na2 = fmaf(a.z, a.z, na2);
                dot = fmaf(a.w, pq.w, dot); na2 = fmaf(a.w, a.w, na2);
            }
            float sim = dot * (1.0f / sqrtf(na2));
            unsigned long long key =
                ((unsigned long long)ordf(sim) << 32) | (unsigned)(~r);
#pragma unroll
            for (int off = 1; off < 64; off <<= 1) {
                unsigned long long o = __shfl_xor(key, off);
                if (o > key) key = o;
            }
            if (key > best) best = key;
        }
        const unsigned idx = ~(unsigned)(best & 0xffffffffull);
        out[q * D + tid] = acts[(size_t)idx * D + tid];
    }
}

extern "C" void kernel_launch(void* const* d_in, const int* in_sizes, int n_in,
                              void* d_out, int out_size, void* d_ws, size_t ws_size,
                              hipStream_t stream)
{
    const float* pred = (const float*)d_in[0];   // (32,4,64)
    const float* acts = (const float*)d_in[1];   // (1000000,64)
    long n0 = in_sizes[0], n1 = in_sizes[1];
    if (n0 > n1) {                                // defensive: acts is the big one
        const float* t = pred; pred = acts; acts = t;
        long tt = n0; n0 = n1; n1 = tt;
    }
    const int N      = (int)(n1 / D);
    const int ntiles = N / TS;                    // 1e6/64 = 15625

    float* tmax = (float*)d_ws;                   // [q][tile]: 128*15625*4 = 8 MB
    float* out  = (float*)d_out;

    k1_score<<<dim3(768), dim3(256), 0, stream>>>(pred, acts, tmax, ntiles);
    k2_rescore<<<dim3(NQ), dim3(256), 0, stream>>>(pred, acts, tmax, out, ntiles);
}